// Round 1
// baseline (200.630 us; speedup 1.0000x reference)
//
#include <hip/hip_runtime.h>

#define ALPHA 0.5f
#define NCLS 86
#define FEAT 256
#define NTOT 131072

// main kernel geometry
constexpr int MAX_NCHUNK = 128;   // sample chunks (power of two)
constexpr int COLG = 2;           // column groups of 128 cols each
constexpr int BLOCK = 1024;       // 16 waves; each wave = 1 sample x 128 cols (float2/lane)

// ws layout (floats): [0] loss accum, [1..86] counts, [128 ...] partials[nchunk][86*256]

__global__ __launch_bounds__(BLOCK) void ctc_main(
    const float2* __restrict__ feat2, const int* __restrict__ labels,
    float* __restrict__ loss_ws, float* __restrict__ counts_ws,
    float* __restrict__ partials, int spc)
{
    __shared__ float lsum[NCLS * 128];
    __shared__ float lcnt[NCLS];
    __shared__ float lred[16];

    const int chunk = blockIdx.x >> 1;
    const int g     = blockIdx.x & 1;   // column group: cols [g*128, g*128+128)

    for (int i = threadIdx.x; i < NCLS * 128; i += BLOCK) lsum[i] = 0.f;
    if (threadIdx.x < NCLS) lcnt[threadIdx.x] = 0.f;
    __syncthreads();

    const int wave = threadIdx.x >> 6;
    const int lane = threadIdx.x & 63;
    const long base = (long)chunk * spc;

    float acc = 0.f;
    for (int it = wave; it < spc; it += 16) {
        const long s = base + it;
        const int lab = labels[s];
        const float2 v = feat2[s * 128 + g * 64 + lane];
        acc += v.x * v.x + v.y * v.y;
        atomicAdd(&lsum[lab * 128 + 2 * lane], v.x);
        atomicAdd(&lsum[lab * 128 + 2 * lane + 1], v.y);
        if (g == 0 && lane == 0) atomicAdd(&lcnt[lab], 1.f);
    }

    // reduce sum(f^2) across block
    for (int off = 32; off; off >>= 1) acc += __shfl_down(acc, off, 64);
    if (lane == 0) lred[wave] = acc;
    __syncthreads();   // also guarantees all LDS atomics are done
    if (threadIdx.x == 0) {
        float t = 0.f;
        for (int w = 0; w < 16; ++w) t += lred[w];
        atomicAdd(loss_ws, 0.5f * t);
    }

    // flush per-class partial sums (deterministic, non-atomic)
    float* dst = partials + (size_t)chunk * (NCLS * FEAT) + g * 128;
    for (int i = threadIdx.x; i < NCLS * 128; i += BLOCK) {
        const int c = i >> 7, col = i & 127;
        dst[c * FEAT + col] = lsum[i];
    }
    if (g == 0 && threadIdx.x < NCLS)
        atomicAdd(&counts_ws[threadIdx.x], lcnt[threadIdx.x]);
}

__global__ __launch_bounds__(256) void ctc_finalize(
    const float* __restrict__ centers, const float* __restrict__ partials,
    const float* __restrict__ counts_ws, float* __restrict__ loss_ws,
    float* __restrict__ out_centers, int nchunk)
{
    // grid: NCLS*4 blocks; block = 4 k-groups x 64 cols
    const int c       = blockIdx.x >> 2;
    const int colbase = (blockIdx.x & 3) * 64;
    const int kq      = threadIdx.x >> 6;
    const int lane    = threadIdx.x & 63;
    const int col     = colbase + lane;

    float S = 0.f;
    for (int k = kq; k < nchunk; k += 4)
        S += partials[(size_t)k * (NCLS * FEAT) + c * FEAT + col];

    __shared__ float lds[4][64];
    lds[kq][lane] = S;
    __syncthreads();
    if (threadIdx.x < 64) {
        S = lds[0][lane] + lds[1][lane] + lds[2][lane] + lds[3][lane];
        const float n  = counts_ws[c];
        const float cc = centers[c * FEAT + col];
        out_centers[c * FEAT + col] = cc + ALPHA * (S - n * cc) / (1.f + n);
        // loss correction terms: -S*c + 0.5*n*c^2
        float corr = 0.5f * n * cc * cc - S * cc;
        for (int off = 32; off; off >>= 1) corr += __shfl_down(corr, off, 64);
        if (lane == 0) atomicAdd(loss_ws, corr);
    }
}

__global__ void ctc_loss_write(const float* __restrict__ loss_ws,
                               float* __restrict__ out)
{
    out[0] = loss_ws[0];
}

extern "C" void kernel_launch(void* const* d_in, const int* in_sizes, int n_in,
                              void* d_out, int out_size, void* d_ws, size_t ws_size,
                              hipStream_t stream)
{
    const float* feat    = (const float*)d_in[0];
    const int*   labels  = (const int*)d_in[1];
    const float* centers = (const float*)d_in[2];
    float* out = (float*)d_out;
    float* ws  = (float*)d_ws;

    float* loss_ws   = ws;        // 1 float
    float* counts_ws = ws + 1;    // 86 floats
    float* partials  = ws + 128;  // nchunk * 22016 floats

    int nchunk = MAX_NCHUNK;
    while (nchunk > 1 &&
           (size_t)(128 + (size_t)nchunk * NCLS * FEAT) * sizeof(float) > ws_size)
        nchunk >>= 1;
    const int spc = NTOT / nchunk;

    hipMemsetAsync(d_ws, 0, 128 * sizeof(float), stream);

    ctc_main<<<nchunk * COLG, BLOCK, 0, stream>>>(
        (const float2*)feat, labels, loss_ws, counts_ws, partials, spc);

    ctc_finalize<<<NCLS * 4, 256, 0, stream>>>(
        centers, partials, counts_ws, loss_ws, out + 1, nchunk);

    ctc_loss_write<<<1, 1, 0, stream>>>(loss_ws, out);
}

// Round 3
// 38.310 us; speedup vs baseline: 5.2370x; 5.2370x over previous
//
#include <hip/hip_runtime.h>

#define ALPHA 0.5f
#define NCLS 86
#define FEAT 256
#define NTOT 131072

constexpr int K   = 32;          // sample chunks
constexpr int BLK = 256;         // 4 waves per block
constexpr int CH  = NTOT / K;    // 4096 samples per chunk
constexpr int WCH = CH / 4;      // 1024 samples per wave

// ws layout (floats):
//   S_part   [K][NCLS][FEAT]   = 704512
//   cnt_part [K][NCLS]         = 2752
//   l2_part  [K][NCLS]         = 2752
//   class_loss [NCLS]          = 86
constexpr size_t WS_S    = 0;
constexpr size_t WS_CNT  = (size_t)K * NCLS * FEAT;
constexpr size_t WS_L2   = WS_CNT + (size_t)K * NCLS;
constexpr size_t WS_CLS  = WS_L2 + (size_t)K * NCLS;

__global__ __launch_bounds__(BLK) void ctc_main(
    const float4* __restrict__ feat4, const int* __restrict__ labels,
    float* __restrict__ S_part, float* __restrict__ cnt_part,
    float* __restrict__ l2_part)
{
    const int k = blockIdx.x % K;   // sample chunk
    const int c = blockIdx.x / K;   // class
    const int wave = threadIdx.x >> 6;
    const int lane = threadIdx.x & 63;

    const int wbase = k * CH + wave * WCH;

    float4 acc = {0.f, 0.f, 0.f, 0.f};
    float  acc2 = 0.f;
    int    cnt  = 0;   // wave-uniform (ballot popcount) — do NOT lane-reduce

    for (int it = 0; it < WCH; it += 64) {
        const int lab = labels[wbase + it + lane];
        unsigned long long m = __ballot(lab == c);
        cnt += __popcll(m);
        while (m) {
            const int b = (int)__ffsll((long long)m) - 1;
            m &= m - 1;
            const float4 v = feat4[(size_t)(wbase + it + b) * 64 + lane];
            acc.x += v.x; acc.y += v.y; acc.z += v.z; acc.w += v.w;
            acc2  += v.x * v.x + v.y * v.y + v.z * v.z + v.w * v.w;
        }
    }

    // reduce acc2 (per-lane distinct features) within wave
    for (int off = 32; off; off >>= 1)
        acc2 += __shfl_down(acc2, off, 64);

    __shared__ float4 ls4[4][64];
    __shared__ float  lcnt[4], ll2[4];
    ls4[wave][lane] = acc;
    if (lane == 0) { lcnt[wave] = (float)cnt; ll2[wave] = acc2; }
    __syncthreads();

    // 256 threads: sum the 4 wave-accumulators elementwise, write S partial
    const int t = threadIdx.x;
    const float* lf = (const float*)ls4;   // [4][256], feature t = lane*4+comp
    const float s = lf[t] + lf[FEAT + t] + lf[2 * FEAT + t] + lf[3 * FEAT + t];
    S_part[((size_t)k * NCLS + c) * FEAT + t] = s;
    if (t == 0) {
        cnt_part[k * NCLS + c] = lcnt[0] + lcnt[1] + lcnt[2] + lcnt[3];
        l2_part[k * NCLS + c]  = ll2[0] + ll2[1] + ll2[2] + ll2[3];
    }
}

__global__ __launch_bounds__(256) void ctc_finalize(
    const float* __restrict__ centers, const float* __restrict__ S_part,
    const float* __restrict__ cnt_part, const float* __restrict__ l2_part,
    float* __restrict__ class_loss, float* __restrict__ out_centers)
{
    const int c = blockIdx.x;
    const int t = threadIdx.x;

    float S = 0.f;
    for (int k = 0; k < K; ++k)
        S += S_part[((size_t)k * NCLS + c) * FEAT + t];

    __shared__ float sn, sl2;
    if (t == 0) {
        float a = 0.f, b = 0.f;
        for (int k = 0; k < K; ++k) {
            a += cnt_part[k * NCLS + c];
            b += l2_part[k * NCLS + c];
        }
        sn = a; sl2 = b;
    }
    __syncthreads();

    const float n  = sn;
    const float cc = centers[c * FEAT + t];
    out_centers[c * FEAT + t] = cc + ALPHA * (S - n * cc) / (1.f + n);

    // per-class loss contribution: 0.5*sum(f^2) + 0.5*n*|cc|^2 - S.cc
    float part = 0.5f * n * cc * cc - S * cc;
    for (int off = 32; off; off >>= 1) part += __shfl_down(part, off, 64);

    __shared__ float red[4];
    const int wv = t >> 6, ln = t & 63;
    if (ln == 0) red[wv] = part;
    __syncthreads();
    if (t == 0)
        class_loss[c] = red[0] + red[1] + red[2] + red[3] + 0.5f * sl2;
}

__global__ void ctc_loss_write(const float* __restrict__ class_loss,
                               float* __restrict__ out)
{
    const int l = threadIdx.x;   // 64 threads, one wave
    float v = (l < NCLS) ? class_loss[l] : 0.f;
    if (l + 64 < NCLS) v += class_loss[l + 64];
    for (int off = 32; off; off >>= 1) v += __shfl_down(v, off, 64);
    if (l == 0) out[0] = v;
}

extern "C" void kernel_launch(void* const* d_in, const int* in_sizes, int n_in,
                              void* d_out, int out_size, void* d_ws, size_t ws_size,
                              hipStream_t stream)
{
    const float* feat    = (const float*)d_in[0];
    const int*   labels  = (const int*)d_in[1];
    const float* centers = (const float*)d_in[2];
    float* out = (float*)d_out;
    float* ws  = (float*)d_ws;

    float* S_part     = ws + WS_S;
    float* cnt_part   = ws + WS_CNT;
    float* l2_part    = ws + WS_L2;
    float* class_loss = ws + WS_CLS;

    ctc_main<<<NCLS * K, BLK, 0, stream>>>(
        (const float4*)feat, labels, S_part, cnt_part, l2_part);

    ctc_finalize<<<NCLS, 256, 0, stream>>>(
        centers, S_part, cnt_part, l2_part, class_loss, out + 1);

    ctc_loss_write<<<1, 64, 0, stream>>>(class_loss, out);
}

// Round 4
// 35.812 us; speedup vs baseline: 5.6024x; 1.0698x over previous
//
#include <hip/hip_runtime.h>

#define ALPHA 0.5f
#define NCLS 86
#define FEAT 256
#define NTOT 131072

constexpr int K   = 64;          // sample chunks
constexpr int CH  = NTOT / K;    // 2048 samples per chunk (one wave each)
constexpr int ITS = CH / 4 / 64; // 8 int4-label iterations per wave

// ws layout (floats):
//   S_part   [NCLS][K][FEAT]  = 1409024
//   cnt_part [NCLS][K]        = 5504
//   l2_part  [NCLS][K]        = 5504
//   class_loss [NCLS]         = 86
constexpr size_t WS_S   = 0;
constexpr size_t WS_CNT = (size_t)NCLS * K * FEAT;
constexpr size_t WS_L2  = WS_CNT + (size_t)NCLS * K;
constexpr size_t WS_CLS = WS_L2 + (size_t)NCLS * K;

__global__ __launch_bounds__(64) void ctc_main(
    const float4* __restrict__ feat4, const int4* __restrict__ lab4,
    float4* __restrict__ S_part4, float* __restrict__ cnt_part,
    float* __restrict__ l2_part)
{
    const int k = blockIdx.x % K;   // sample chunk
    const int c = blockIdx.x / K;   // class
    const int lane = threadIdx.x;
    const int base = k * CH;        // first sample of this chunk

    float4 acc = {0.f, 0.f, 0.f, 0.f};
    float  acc2 = 0.f;
    int    cnt  = 0;   // wave-uniform (ballot popcounts)

    for (int it = 0; it < ITS * 64; it += 64) {
        // lane covers samples base + (it+lane)*4 .. +3
        const int4 L = lab4[base / 4 + it + lane];
        unsigned long long m0 = __ballot(L.x == c);
        unsigned long long m1 = __ballot(L.y == c);
        unsigned long long m2 = __ballot(L.z == c);
        unsigned long long m3 = __ballot(L.w == c);
        cnt += __popcll(m0) + __popcll(m1) + __popcll(m2) + __popcll(m3);
        // bit b of mask j  <->  sample base + (it+b)*4 + j
#define DRAIN(mm, j)                                                        \
        while (mm) {                                                       \
            const int b = (int)__ffsll((long long)mm) - 1;                 \
            mm &= mm - 1;                                                  \
            const float4 v = feat4[(size_t)(base + (it + b) * 4 + j) * 64  \
                                   + lane];                                \
            acc.x += v.x; acc.y += v.y; acc.z += v.z; acc.w += v.w;        \
            acc2  += v.x * v.x + v.y * v.y + v.z * v.z + v.w * v.w;        \
        }
        DRAIN(m0, 0) DRAIN(m1, 1) DRAIN(m2, 2) DRAIN(m3, 3)
#undef DRAIN
    }

    // acc holds features 4*lane .. 4*lane+3  ->  write partial row directly
    S_part4[((size_t)c * K + k) * 64 + lane] = acc;

    for (int off = 32; off; off >>= 1)
        acc2 += __shfl_down(acc2, off, 64);
    if (lane == 0) {
        cnt_part[c * K + k] = (float)cnt;
        l2_part[c * K + k]  = acc2;
    }
}

__global__ __launch_bounds__(256) void ctc_finalize(
    const float* __restrict__ centers, const float* __restrict__ S_part,
    const float* __restrict__ cnt_part, const float* __restrict__ l2_part,
    float* __restrict__ class_loss, float* __restrict__ out_centers)
{
    const int c = blockIdx.x;
    const int t = threadIdx.x;

    float S = 0.f;
    for (int k = 0; k < K; ++k)
        S += S_part[((size_t)c * K + k) * FEAT + t];

    __shared__ float sn, sl2;
    if (t == 0) {
        float a = 0.f, b = 0.f;
        for (int k = 0; k < K; ++k) {
            a += cnt_part[c * K + k];
            b += l2_part[c * K + k];
        }
        sn = a; sl2 = b;
    }
    __syncthreads();

    const float n  = sn;
    const float cc = centers[c * FEAT + t];
    out_centers[c * FEAT + t] = cc + ALPHA * (S - n * cc) / (1.f + n);

    // per-class loss contribution: 0.5*sum(f^2) + 0.5*n*|cc|^2 - S.cc
    float part = 0.5f * n * cc * cc - S * cc;
    for (int off = 32; off; off >>= 1) part += __shfl_down(part, off, 64);

    __shared__ float red[4];
    const int wv = t >> 6, ln = t & 63;
    if (ln == 0) red[wv] = part;
    __syncthreads();
    if (t == 0)
        class_loss[c] = red[0] + red[1] + red[2] + red[3] + 0.5f * sl2;
}

__global__ void ctc_loss_write(const float* __restrict__ class_loss,
                               float* __restrict__ out)
{
    const int l = threadIdx.x;   // 64 threads, one wave
    float v = (l < NCLS) ? class_loss[l] : 0.f;
    if (l + 64 < NCLS) v += class_loss[l + 64];
    for (int off = 32; off; off >>= 1) v += __shfl_down(v, off, 64);
    if (l == 0) out[0] = v;
}

extern "C" void kernel_launch(void* const* d_in, const int* in_sizes, int n_in,
                              void* d_out, int out_size, void* d_ws, size_t ws_size,
                              hipStream_t stream)
{
    const float* feat    = (const float*)d_in[0];
    const int*   labels  = (const int*)d_in[1];
    const float* centers = (const float*)d_in[2];
    float* out = (float*)d_out;
    float* ws  = (float*)d_ws;

    float* S_part     = ws + WS_S;
    float* cnt_part   = ws + WS_CNT;
    float* l2_part    = ws + WS_L2;
    float* class_loss = ws + WS_CLS;

    ctc_main<<<NCLS * K, 64, 0, stream>>>(
        (const float4*)feat, (const int4*)labels,
        (float4*)S_part, cnt_part, l2_part);

    ctc_finalize<<<NCLS, 256, 0, stream>>>(
        centers, S_part, cnt_part, l2_part, class_loss, out + 1);

    ctc_loss_write<<<1, 64, 0, stream>>>(class_loss, out);
}

// Round 5
// 34.022 us; speedup vs baseline: 5.8970x; 1.0526x over previous
//
#include <hip/hip_runtime.h>

#define ALPHA 0.5f
#define NCLS 86
#define FEAT 256
#define NTOT 131072

constexpr int K   = 64;          // sample chunks
constexpr int CH  = NTOT / K;    // 2048 samples per chunk (one wave each)
constexpr int L4  = CH / 4;      // 512 int4 label-packs per chunk

// ws layout (floats):
//   S_part   [NCLS][K][FEAT]  = 1409024
//   cnt_part [NCLS][K]        = 5504
//   l2_part  [NCLS][K]        = 5504
//   class_loss [NCLS]         = 86
constexpr size_t WS_S   = 0;
constexpr size_t WS_CNT = (size_t)NCLS * K * FEAT;
constexpr size_t WS_L2  = WS_CNT + (size_t)NCLS * K;
constexpr size_t WS_CLS = WS_L2 + (size_t)NCLS * K;

// 128-thread blocks (2 waves): 2752 blocks = 10.75/CU, under the 16-wg/CU
// cap -> whole grid co-resident in ONE scheduling round (~21.5 waves/CU).
__global__ __launch_bounds__(128) void ctc_main(
    const float4* __restrict__ feat4, const int4* __restrict__ lab4,
    float4* __restrict__ S_part4, float* __restrict__ cnt_part,
    float* __restrict__ l2_part)
{
    const int wave = threadIdx.x >> 6;
    const int lane = threadIdx.x & 63;
    const int pair = blockIdx.x * 2 + wave;   // (c,k) pair, = c*K + k
    const int k = pair % K;
    const int c = pair / K;
    const int base = k * CH;                  // first sample of this chunk

    const int4* lp = lab4 + base / 4 + lane;

    float4 acc = {0.f, 0.f, 0.f, 0.f};
    float  acc2 = 0.f;
    int    cnt  = 0;   // wave-uniform (ballot popcounts)

    int4 L = lp[0];    // prefetched labels for current iteration
    for (int it = 0; it < L4; it += 64) {
        const int4 Lc = L;
        if (it + 64 < L4) L = lp[it + 64];    // prefetch next iter's labels
        unsigned long long m0 = __ballot(Lc.x == c);
        unsigned long long m1 = __ballot(Lc.y == c);
        unsigned long long m2 = __ballot(Lc.z == c);
        unsigned long long m3 = __ballot(Lc.w == c);
        cnt += __popcll(m0) + __popcll(m1) + __popcll(m2) + __popcll(m3);
        // bit b of mask j  <->  sample base + (it+b)*4 + j
        // 2-deep drain: issue two row-loads before their accumulates
#define ACCUM(v)                                                           \
        { acc.x += v.x; acc.y += v.y; acc.z += v.z; acc.w += v.w;          \
          acc2  += v.x * v.x + v.y * v.y + v.z * v.z + v.w * v.w; }
#define DRAIN(mm, j)                                                       \
        while (mm) {                                                       \
            const int b0 = (int)__ffsll((long long)mm) - 1; mm &= mm - 1;  \
            if (mm) {                                                      \
                const int b1 = (int)__ffsll((long long)mm) - 1;            \
                mm &= mm - 1;                                              \
                const float4 v0 =                                          \
                    feat4[(size_t)(base + (it + b0) * 4 + j) * 64 + lane]; \
                const float4 v1 =                                          \
                    feat4[(size_t)(base + (it + b1) * 4 + j) * 64 + lane]; \
                ACCUM(v0) ACCUM(v1)                                        \
            } else {                                                       \
                const float4 v0 =                                          \
                    feat4[(size_t)(base + (it + b0) * 4 + j) * 64 + lane]; \
                ACCUM(v0)                                                  \
            }                                                              \
        }
        DRAIN(m0, 0) DRAIN(m1, 1) DRAIN(m2, 2) DRAIN(m3, 3)
#undef DRAIN
#undef ACCUM
    }

    // acc holds features 4*lane .. 4*lane+3  ->  write partial row directly
    S_part4[(size_t)pair * 64 + lane] = acc;

    for (int off = 32; off; off >>= 1)
        acc2 += __shfl_down(acc2, off, 64);
    if (lane == 0) {
        cnt_part[pair] = (float)cnt;
        l2_part[pair]  = acc2;
    }
}

__global__ __launch_bounds__(256) void ctc_finalize(
    const float* __restrict__ centers, const float* __restrict__ S_part,
    const float* __restrict__ cnt_part, const float* __restrict__ l2_part,
    float* __restrict__ class_loss, float* __restrict__ out_centers)
{
    const int c = blockIdx.x;
    const int t = threadIdx.x;

    float S = 0.f;
    for (int k = 0; k < K; ++k)
        S += S_part[((size_t)c * K + k) * FEAT + t];

    __shared__ float sn, sl2;
    if (t == 0) {
        float a = 0.f, b = 0.f;
        for (int k = 0; k < K; ++k) {
            a += cnt_part[c * K + k];
            b += l2_part[c * K + k];
        }
        sn = a; sl2 = b;
    }
    __syncthreads();

    const float n  = sn;
    const float cc = centers[c * FEAT + t];
    out_centers[c * FEAT + t] = cc + ALPHA * (S - n * cc) / (1.f + n);

    // per-class loss contribution: 0.5*sum(f^2) + 0.5*n*|cc|^2 - S.cc
    float part = 0.5f * n * cc * cc - S * cc;
    for (int off = 32; off; off >>= 1) part += __shfl_down(part, off, 64);

    __shared__ float red[4];
    const int wv = t >> 6, ln = t & 63;
    if (ln == 0) red[wv] = part;
    __syncthreads();
    if (t == 0)
        class_loss[c] = red[0] + red[1] + red[2] + red[3] + 0.5f * sl2;
}

__global__ void ctc_loss_write(const float* __restrict__ class_loss,
                               float* __restrict__ out)
{
    const int l = threadIdx.x;   // 64 threads, one wave
    float v = (l < NCLS) ? class_loss[l] : 0.f;
    if (l + 64 < NCLS) v += class_loss[l + 64];
    for (int off = 32; off; off >>= 1) v += __shfl_down(v, off, 64);
    if (l == 0) out[0] = v;
}

extern "C" void kernel_launch(void* const* d_in, const int* in_sizes, int n_in,
                              void* d_out, int out_size, void* d_ws, size_t ws_size,
                              hipStream_t stream)
{
    const float* feat    = (const float*)d_in[0];
    const int*   labels  = (const int*)d_in[1];
    const float* centers = (const float*)d_in[2];
    float* out = (float*)d_out;
    float* ws  = (float*)d_ws;

    float* S_part     = ws + WS_S;
    float* cnt_part   = ws + WS_CNT;
    float* l2_part    = ws + WS_L2;
    float* class_loss = ws + WS_CLS;

    ctc_main<<<NCLS * K / 2, 128, 0, stream>>>(
        (const float4*)feat, (const int4*)labels,
        (float4*)S_part, cnt_part, l2_part);

    ctc_finalize<<<NCLS, 256, 0, stream>>>(
        centers, S_part, cnt_part, l2_part, class_loss, out + 1);

    ctc_loss_write<<<1, 64, 0, stream>>>(class_loss, out);
}